// Round 1
// baseline (939.607 us; speedup 1.0000x reference)
//
#include <hip/hip_runtime.h>
#include <hip/hip_bf16.h>

#define N_NODES 100000
#define N_EDGES 1600000
#define IN_F 64
#define H_F 128

// ---------------- CSR build ----------------

__global__ __launch_bounds__(256) void count_deg_kernel(const int* __restrict__ ei, int* __restrict__ deg) {
    int e = blockIdx.x * 256 + threadIdx.x;
    if (e < N_EDGES) {
        int d = ei[N_EDGES + e];
        atomicAdd(&deg[d], 1);
    }
}

#define SCAN_ELEMS 1024
// phase A: per-block sums of deg
__global__ __launch_bounds__(256) void scan_a_kernel(const int* __restrict__ deg, int* __restrict__ bsum) {
    __shared__ int lds[256];
    int tid = threadIdx.x;
    int base = blockIdx.x * SCAN_ELEMS + tid * 4;
    int s = 0;
    #pragma unroll
    for (int i = 0; i < 4; i++) {
        int idx = base + i;
        s += (idx < N_NODES) ? deg[idx] : 0;
    }
    lds[tid] = s;
    __syncthreads();
    for (int off = 128; off; off >>= 1) {
        if (tid < off) lds[tid] += lds[tid + off];
        __syncthreads();
    }
    if (tid == 0) bsum[blockIdx.x] = lds[0];
}

// phase B: serial exclusive scan of block sums (nb ~ 98, negligible)
__global__ void scan_b_kernel(int* __restrict__ bsum, int nb) {
    if (threadIdx.x == 0 && blockIdx.x == 0) {
        int acc = 0;
        for (int i = 0; i < nb; i++) { int v = bsum[i]; bsum[i] = acc; acc += v; }
    }
}

// phase C: full exclusive scan -> row_ptr
__global__ __launch_bounds__(256) void scan_c_kernel(const int* __restrict__ deg, const int* __restrict__ bsum,
                                                     int* __restrict__ row_ptr) {
    __shared__ int lds[256];
    int tid = threadIdx.x;
    int base = blockIdx.x * SCAN_ELEMS + tid * 4;
    int v[4];
    int s = 0;
    #pragma unroll
    for (int i = 0; i < 4; i++) {
        int idx = base + i;
        v[i] = (idx < N_NODES) ? deg[idx] : 0;
        s += v[i];
    }
    lds[tid] = s;
    __syncthreads();
    // Hillis-Steele inclusive scan over 256 thread sums
    for (int off = 1; off < 256; off <<= 1) {
        int y = 0;
        if (tid >= off) y = lds[tid - off];
        __syncthreads();
        if (tid >= off) lds[tid] += y;
        __syncthreads();
    }
    int run = bsum[blockIdx.x] + lds[tid] - s;   // exclusive offset for this thread
    #pragma unroll
    for (int i = 0; i < 4; i++) {
        int idx = base + i;
        if (idx < N_NODES) row_ptr[idx] = run;
        run += v[i];
    }
    if (blockIdx.x == 0 && tid == 0) row_ptr[N_NODES] = N_EDGES;
}

__global__ __launch_bounds__(256) void fill_csr_kernel(const int* __restrict__ ei, const int* __restrict__ row_ptr,
                                                       int* __restrict__ cnt, int* __restrict__ col) {
    int e = blockIdx.x * 256 + threadIdx.x;
    if (e < N_EDGES) {
        int d = ei[N_EDGES + e];
        int pos = row_ptr[d] + atomicAdd(&cnt[d], 1);
        col[pos] = ei[e];
    }
}

__global__ __launch_bounds__(256) void deginv_kernel(const int* __restrict__ deg, float* __restrict__ deg_inv) {
    int i = blockIdx.x * 256 + threadIdx.x;
    if (i < N_NODES) deg_inv[i] = 1.0f / fmaxf((float)deg[i], 1.0f);
}

// ---------------- GEMM: C[M x Nc] = A[M x K] @ B[K x *], tiles of 128x128 ----------------
// BK=16, 256 threads, 8x8 microtile per thread.

__global__ __launch_bounds__(256) void gemm_kernel(const float* __restrict__ A, const float* __restrict__ B,
                                                   float* __restrict__ C, int M, int K, int ldb, int ldc,
                                                   int accumulate) {
    __shared__ float As[16][128];
    __shared__ float Bs[16][128];
    int tid = threadIdx.x;
    int m0 = blockIdx.x * 128;
    int n0 = blockIdx.y * 128;
    int tx = tid & 15;   // n dim
    int ty = tid >> 4;   // m dim

    float acc[8][8];
    #pragma unroll
    for (int i = 0; i < 8; i++)
        #pragma unroll
        for (int j = 0; j < 8; j++) acc[i][j] = 0.f;

    int a_r = tid >> 1;
    int a_k = (tid & 1) * 8;
    int b_k = tid >> 4;
    int b_n = (tid & 15) * 8;

    for (int k0 = 0; k0 < K; k0 += 16) {
        int ar = m0 + a_r; if (ar > M - 1) ar = M - 1;
        const float* ap = A + (size_t)ar * K + k0 + a_k;
        float4 av0 = *(const float4*)ap;
        float4 av1 = *(const float4*)(ap + 4);
        const float* bp = B + (size_t)(k0 + b_k) * ldb + n0 + b_n;
        float4 bv0 = *(const float4*)bp;
        float4 bv1 = *(const float4*)(bp + 4);

        __syncthreads();
        As[a_k + 0][a_r] = av0.x; As[a_k + 1][a_r] = av0.y;
        As[a_k + 2][a_r] = av0.z; As[a_k + 3][a_r] = av0.w;
        As[a_k + 4][a_r] = av1.x; As[a_k + 5][a_r] = av1.y;
        As[a_k + 6][a_r] = av1.z; As[a_k + 7][a_r] = av1.w;
        *(float4*)&Bs[b_k][b_n] = bv0;
        *(float4*)&Bs[b_k][b_n + 4] = bv1;
        __syncthreads();

        #pragma unroll
        for (int kk = 0; kk < 16; kk++) {
            float a[8], b[8];
            *(float4*)(a)     = *(const float4*)&As[kk][ty * 4];
            *(float4*)(a + 4) = *(const float4*)&As[kk][ty * 4 + 64];
            *(float4*)(b)     = *(const float4*)&Bs[kk][tx * 4];
            *(float4*)(b + 4) = *(const float4*)&Bs[kk][tx * 4 + 64];
            #pragma unroll
            for (int i = 0; i < 8; i++)
                #pragma unroll
                for (int j = 0; j < 8; j++) acc[i][j] = fmaf(a[i], b[j], acc[i][j]);
        }
    }

    #pragma unroll
    for (int i = 0; i < 8; i++) {
        int m = m0 + ty * 4 + (i & 3) + ((i >> 2) << 6);
        if (m < M) {
            float* cp = C + (size_t)m * ldc + n0;
            float4 v0 = make_float4(acc[i][0], acc[i][1], acc[i][2], acc[i][3]);
            float4 v1 = make_float4(acc[i][4], acc[i][5], acc[i][6], acc[i][7]);
            if (accumulate) {
                float4 o0 = *(const float4*)(cp + tx * 4);
                float4 o1 = *(const float4*)(cp + 64 + tx * 4);
                v0.x += o0.x; v0.y += o0.y; v0.z += o0.z; v0.w += o0.w;
                v1.x += o1.x; v1.y += o1.y; v1.z += o1.z; v1.w += o1.w;
            }
            *(float4*)(cp + tx * 4) = v0;
            *(float4*)(cp + 64 + tx * 4) = v1;
        }
    }
}

// ---------------- concat two KxH weight matrices into Kx256 ----------------
__global__ __launch_bounds__(256) void wcat_kernel(const float* __restrict__ X, const float* __restrict__ Y,
                                                   float* __restrict__ W, int K) {
    int idx = blockIdx.x * 256 + threadIdx.x;
    if (idx < K * 256) {
        int k = idx >> 8;
        int n = idx & 255;
        W[idx] = (n < 128) ? X[k * 128 + n] : Y[k * 128 + n - 128];
    }
}

// ---------------- aggregation: mean of x[src] (64 feats) ----------------
__global__ __launch_bounds__(256) void agg64_kernel(const float* __restrict__ x, const int* __restrict__ row_ptr,
                                                    const int* __restrict__ col, const float* __restrict__ deg_inv,
                                                    float* __restrict__ aggx) {
    int tid = threadIdx.x;
    int g = tid >> 6;
    int f = tid & 63;
    int i = blockIdx.x * 4 + g;
    if (i >= N_NODES) return;
    int s = row_ptr[i], e = row_ptr[i + 1];
    float acc = 0.f;
    int t = s;
    for (; t + 3 < e; t += 4) {
        int j0 = col[t], j1 = col[t + 1], j2 = col[t + 2], j3 = col[t + 3];
        acc += x[(size_t)j0 * 64 + f];
        acc += x[(size_t)j1 * 64 + f];
        acc += x[(size_t)j2 * 64 + f];
        acc += x[(size_t)j3 * 64 + f];
    }
    for (; t < e; t++) acc += x[(size_t)col[t] * 64 + f];
    aggx[(size_t)i * 64 + f] = acc * deg_inv[i];
}

// ---------------- layers 2/3: h[i] = relu(deg_inv*sum G[j,0:128] + G[i,128:256] + b) ----------------
__global__ __launch_bounds__(256) void agg128_relu_kernel(const float* __restrict__ G, const int* __restrict__ row_ptr,
                                                          const int* __restrict__ col, const float* __restrict__ deg_inv,
                                                          const float* __restrict__ bias, float* __restrict__ h) {
    int tid = threadIdx.x;
    int g = tid >> 7;
    int f = tid & 127;
    int i = blockIdx.x * 2 + g;
    if (i >= N_NODES) return;
    int s = row_ptr[i], e = row_ptr[i + 1];
    float acc = 0.f;
    int t = s;
    for (; t + 3 < e; t += 4) {
        int j0 = col[t], j1 = col[t + 1], j2 = col[t + 2], j3 = col[t + 3];
        acc += G[(size_t)j0 * 256 + f];
        acc += G[(size_t)j1 * 256 + f];
        acc += G[(size_t)j2 * 256 + f];
        acc += G[(size_t)j3 * 256 + f];
    }
    for (; t < e; t++) acc += G[(size_t)col[t] * 256 + f];
    float y = acc * deg_inv[i] + G[(size_t)i * 256 + 128 + f] + bias[f];
    h[(size_t)i * 128 + f] = fmaxf(y, 0.f);
}

// ---------------- layer1 epilogue: t=U[:,0:128]+b1 -> LN -> relu -> + U[:,128:256]+bres ----------------
__global__ __launch_bounds__(256) void ln_kernel(const float* __restrict__ U, const float* __restrict__ b1,
                                                 const float* __restrict__ ln_g, const float* __restrict__ ln_b,
                                                 const float* __restrict__ bres, float* __restrict__ h) {
    int tid = threadIdx.x;
    int grp = tid >> 7;       // node within block
    int f = tid & 127;
    int i = blockIdx.x * 2 + grp;
    bool valid = i < N_NODES;
    float t = 0.f;
    if (valid) t = U[(size_t)i * 256 + f] + b1[f];
    float s = t, s2 = t * t;
    #pragma unroll
    for (int off = 32; off; off >>= 1) {
        s += __shfl_down(s, off);
        s2 += __shfl_down(s2, off);
    }
    __shared__ float rs[4], rs2[4];
    int wave = tid >> 6;
    if ((tid & 63) == 0) { rs[wave] = s; rs2[wave] = s2; }
    __syncthreads();
    float sum = rs[grp * 2] + rs[grp * 2 + 1];
    float sumsq = rs2[grp * 2] + rs2[grp * 2 + 1];
    float mu = sum * (1.f / 128.f);
    float var = sumsq * (1.f / 128.f) - mu * mu;
    float r = rsqrtf(var + 1e-5f);
    if (valid) {
        float y = (t - mu) * r * ln_g[f] + ln_b[f];
        y = fmaxf(y, 0.f);
        y += U[(size_t)i * 256 + 128 + f] + bres[f];
        h[(size_t)i * 128 + f] = y;
    }
}

// ---------------- layer4: p = h@Wl4, q = h@Wr4 + b4 (one wave per node) ----------------
__global__ __launch_bounds__(256) void pq_kernel(const float* __restrict__ h, const float* __restrict__ Wl4,
                                                 const float* __restrict__ Wr4, const float* __restrict__ b4,
                                                 float* __restrict__ p, float* __restrict__ q) {
    int tid = threadIdx.x;
    int lane = tid & 63;
    int w = tid >> 6;
    int i = blockIdx.x * 4 + w;
    if (i >= N_NODES) return;
    const float* hr = h + (size_t)i * 128;
    float a = hr[lane], b = hr[64 + lane];
    float pp = a * Wl4[lane] + b * Wl4[64 + lane];
    float qq = a * Wr4[lane] + b * Wr4[64 + lane];
    #pragma unroll
    for (int off = 32; off; off >>= 1) {
        pp += __shfl_down(pp, off);
        qq += __shfl_down(qq, off);
    }
    if (lane == 0) { p[i] = pp; q[i] = qq + b4[0]; }
}

__global__ __launch_bounds__(256) void final_kernel(const float* __restrict__ p, const float* __restrict__ q,
                                                    const int* __restrict__ row_ptr, const int* __restrict__ col,
                                                    const float* __restrict__ deg_inv, float* __restrict__ out) {
    int i = blockIdx.x * 256 + threadIdx.x;
    if (i >= N_NODES) return;
    int s = row_ptr[i], e = row_ptr[i + 1];
    float acc = 0.f;
    for (int t = s; t < e; t++) acc += p[col[t]];
    out[i] = acc * deg_inv[i] + q[i];
}

// ---------------- launch ----------------

extern "C" void kernel_launch(void* const* d_in, const int* in_sizes, int n_in,
                              void* d_out, int out_size, void* d_ws, size_t ws_size,
                              hipStream_t stream) {
    const float* x    = (const float*)d_in[0];
    const int*   ei   = (const int*)d_in[1];
    const float* Wl1  = (const float*)d_in[2];
    const float* Wr1  = (const float*)d_in[3];
    const float* b1   = (const float*)d_in[4];
    const float* ln_g = (const float*)d_in[5];
    const float* ln_b = (const float*)d_in[6];
    const float* Wres = (const float*)d_in[7];
    const float* bres = (const float*)d_in[8];
    const float* Wl2  = (const float*)d_in[9];
    const float* Wr2  = (const float*)d_in[10];
    const float* b2   = (const float*)d_in[11];
    const float* Wl3  = (const float*)d_in[12];
    const float* Wr3  = (const float*)d_in[13];
    const float* b3   = (const float*)d_in[14];
    const float* Wl4  = (const float*)d_in[15];
    const float* Wr4  = (const float*)d_in[16];
    const float* b4   = (const float*)d_in[17];
    float* out = (float*)d_out;

    char* w = (char*)d_ws;
    size_t off = 0;
    auto alloc = [&](size_t bytes) -> void* {
        off = (off + 255) & ~(size_t)255;
        void* pp = w + off;
        off += bytes;
        return pp;
    };

    int*   deg     = (int*)alloc(N_NODES * 4);
    int*   cnt     = (int*)alloc(N_NODES * 4);
    int*   row_ptr = (int*)alloc((N_NODES + 1) * 4);
    int*   bsum    = (int*)alloc(512);
    int*   col     = (int*)alloc(N_EDGES * 4);
    float* deg_inv = (float*)alloc(N_NODES * 4);
    float* Wcat    = (float*)alloc(128 * 256 * 4);
    float* aggx    = (float*)alloc((size_t)N_NODES * 64 * 4);
    float* U       = (float*)alloc((size_t)N_NODES * 256 * 4);
    float* h       = (float*)alloc((size_t)N_NODES * 128 * 4);
    float* p       = (float*)alloc(N_NODES * 4);
    float* q       = (float*)alloc(N_NODES * 4);
    (void)ws_size; (void)n_in; (void)in_sizes; (void)out_size;

    const int EB = (N_EDGES + 255) / 256;               // 6250
    const int NB = (N_NODES + 255) / 256;               // 391
    const int SCB = (N_NODES + SCAN_ELEMS - 1) / SCAN_ELEMS;  // 98
    const int MB = (N_NODES + 127) / 128;               // 782

    // --- CSR build ---
    hipMemsetAsync(deg, 0, N_NODES * 4, stream);
    hipMemsetAsync(cnt, 0, N_NODES * 4, stream);
    count_deg_kernel<<<EB, 256, 0, stream>>>(ei, deg);
    scan_a_kernel<<<SCB, 256, 0, stream>>>(deg, bsum);
    scan_b_kernel<<<1, 64, 0, stream>>>(bsum, SCB);
    scan_c_kernel<<<SCB, 256, 0, stream>>>(deg, bsum, row_ptr);
    fill_csr_kernel<<<EB, 256, 0, stream>>>(ei, row_ptr, cnt, col);
    deginv_kernel<<<NB, 256, 0, stream>>>(deg, deg_inv);

    // --- layer 1 ---
    agg64_kernel<<<(N_NODES + 3) / 4, 256, 0, stream>>>(x, row_ptr, col, deg_inv, aggx);
    wcat_kernel<<<64, 256, 0, stream>>>(Wr1, Wres, Wcat, 64);
    gemm_kernel<<<dim3(MB, 2), 256, 0, stream>>>(x, Wcat, U, N_NODES, 64, 256, 256, 0);
    gemm_kernel<<<dim3(MB, 1), 256, 0, stream>>>(aggx, Wl1, U, N_NODES, 64, 128, 256, 1);
    ln_kernel<<<(N_NODES + 1) / 2, 256, 0, stream>>>(U, b1, ln_g, ln_b, bres, h);

    // --- layer 2 ---
    wcat_kernel<<<128, 256, 0, stream>>>(Wl2, Wr2, Wcat, 128);
    gemm_kernel<<<dim3(MB, 2), 256, 0, stream>>>(h, Wcat, U, N_NODES, 128, 256, 256, 0);
    agg128_relu_kernel<<<(N_NODES + 1) / 2, 256, 0, stream>>>(U, row_ptr, col, deg_inv, b2, h);

    // --- layer 3 ---
    wcat_kernel<<<128, 256, 0, stream>>>(Wl3, Wr3, Wcat, 128);
    gemm_kernel<<<dim3(MB, 2), 256, 0, stream>>>(h, Wcat, U, N_NODES, 128, 256, 256, 0);
    agg128_relu_kernel<<<(N_NODES + 1) / 2, 256, 0, stream>>>(U, row_ptr, col, deg_inv, b3, h);

    // --- layer 4 ---
    pq_kernel<<<(N_NODES + 3) / 4, 256, 0, stream>>>(h, Wl4, Wr4, b4, p, q);
    final_kernel<<<NB, 256, 0, stream>>>(p, q, row_ptr, col, deg_inv, out);
}

// Round 2
// 812.806 us; speedup vs baseline: 1.1560x; 1.1560x over previous
//
#include <hip/hip_runtime.h>
#include <hip/hip_bf16.h>

#define N_NODES 100000
#define N_EDGES 1600000
#define IN_F 64
#define H_F 128

__device__ __forceinline__ unsigned short f2bf(float f) {
    unsigned int u = __float_as_uint(f);
    u = (u + 0x7FFFu + ((u >> 16) & 1u)) >> 16;   // RTNE
    return (unsigned short)u;
}
__device__ __forceinline__ float bf2f(unsigned short b) {
    return __uint_as_float((unsigned int)b << 16);
}

// ---------------- CSR build ----------------

__global__ __launch_bounds__(256) void count_deg_kernel(const int* __restrict__ ei, int* __restrict__ deg) {
    int e = blockIdx.x * 256 + threadIdx.x;
    if (e < N_EDGES) {
        int d = ei[N_EDGES + e];
        atomicAdd(&deg[d], 1);
    }
}

#define SCAN_ELEMS 1024
__global__ __launch_bounds__(256) void scan_a_kernel(const int* __restrict__ deg, int* __restrict__ bsum) {
    __shared__ int lds[256];
    int tid = threadIdx.x;
    int base = blockIdx.x * SCAN_ELEMS + tid * 4;
    int s = 0;
    #pragma unroll
    for (int i = 0; i < 4; i++) {
        int idx = base + i;
        s += (idx < N_NODES) ? deg[idx] : 0;
    }
    lds[tid] = s;
    __syncthreads();
    for (int off = 128; off; off >>= 1) {
        if (tid < off) lds[tid] += lds[tid + off];
        __syncthreads();
    }
    if (tid == 0) bsum[blockIdx.x] = lds[0];
}

__global__ void scan_b_kernel(int* __restrict__ bsum, int nb) {
    if (threadIdx.x == 0 && blockIdx.x == 0) {
        int acc = 0;
        for (int i = 0; i < nb; i++) { int v = bsum[i]; bsum[i] = acc; acc += v; }
    }
}

__global__ __launch_bounds__(256) void scan_c_kernel(const int* __restrict__ deg, const int* __restrict__ bsum,
                                                     int* __restrict__ row_ptr) {
    __shared__ int lds[256];
    int tid = threadIdx.x;
    int base = blockIdx.x * SCAN_ELEMS + tid * 4;
    int v[4];
    int s = 0;
    #pragma unroll
    for (int i = 0; i < 4; i++) {
        int idx = base + i;
        v[i] = (idx < N_NODES) ? deg[idx] : 0;
        s += v[i];
    }
    lds[tid] = s;
    __syncthreads();
    for (int off = 1; off < 256; off <<= 1) {
        int y = 0;
        if (tid >= off) y = lds[tid - off];
        __syncthreads();
        if (tid >= off) lds[tid] += y;
        __syncthreads();
    }
    int run = bsum[blockIdx.x] + lds[tid] - s;
    #pragma unroll
    for (int i = 0; i < 4; i++) {
        int idx = base + i;
        if (idx < N_NODES) row_ptr[idx] = run;
        run += v[i];
    }
    if (blockIdx.x == 0 && tid == 0) row_ptr[N_NODES] = N_EDGES;
}

__global__ __launch_bounds__(256) void fill_csr_kernel(const int* __restrict__ ei, const int* __restrict__ row_ptr,
                                                       int* __restrict__ cnt, int* __restrict__ col) {
    int e = blockIdx.x * 256 + threadIdx.x;
    if (e < N_EDGES) {
        int d = ei[N_EDGES + e];
        int pos = row_ptr[d] + atomicAdd(&cnt[d], 1);
        col[pos] = ei[e];
    }
}

__global__ __launch_bounds__(256) void deginv_kernel(const int* __restrict__ deg, float* __restrict__ deg_inv) {
    int i = blockIdx.x * 256 + threadIdx.x;
    if (i < N_NODES) deg_inv[i] = 1.0f / fmaxf((float)deg[i], 1.0f);
}

// ---------------- x -> bf16 ----------------
__global__ __launch_bounds__(256) void xbf_kernel(const float* __restrict__ x, unsigned short* __restrict__ xb) {
    int idx = blockIdx.x * 256 + threadIdx.x;   // one float4 per thread
    if (idx < N_NODES * IN_F / 4) {
        float4 v = *(const float4*)(x + (size_t)idx * 4);
        ushort4 o;
        o.x = f2bf(v.x); o.y = f2bf(v.y); o.z = f2bf(v.z); o.w = f2bf(v.w);
        *(ushort4*)(xb + (size_t)idx * 4) = o;
    }
}

// ---------------- GEMM: 128x128 tiles, BK=16, 8x8 microtile ----------------
// If Cbf != nullptr and n0 == 0: write bf16 to Cbf (ld 128). fp32 writes go to
// C + m*ldc + (n0 - c_col_off).

__global__ __launch_bounds__(256) void gemm_kernel(const float* __restrict__ A, const float* __restrict__ B,
                                                   float* __restrict__ C, unsigned short* __restrict__ Cbf,
                                                   int M, int K, int ldb, int ldc, int c_col_off,
                                                   int accumulate) {
    __shared__ float As[16][128];
    __shared__ float Bs[16][128];
    int tid = threadIdx.x;
    int m0 = blockIdx.x * 128;
    int n0 = blockIdx.y * 128;
    int tx = tid & 15;   // n dim
    int ty = tid >> 4;   // m dim

    float acc[8][8];
    #pragma unroll
    for (int i = 0; i < 8; i++)
        #pragma unroll
        for (int j = 0; j < 8; j++) acc[i][j] = 0.f;

    int a_r = tid >> 1;
    int a_k = (tid & 1) * 8;
    int b_k = tid >> 4;
    int b_n = (tid & 15) * 8;

    for (int k0 = 0; k0 < K; k0 += 16) {
        int ar = m0 + a_r; if (ar > M - 1) ar = M - 1;
        const float* ap = A + (size_t)ar * K + k0 + a_k;
        float4 av0 = *(const float4*)ap;
        float4 av1 = *(const float4*)(ap + 4);
        const float* bp = B + (size_t)(k0 + b_k) * ldb + n0 + b_n;
        float4 bv0 = *(const float4*)bp;
        float4 bv1 = *(const float4*)(bp + 4);

        __syncthreads();
        As[a_k + 0][a_r] = av0.x; As[a_k + 1][a_r] = av0.y;
        As[a_k + 2][a_r] = av0.z; As[a_k + 3][a_r] = av0.w;
        As[a_k + 4][a_r] = av1.x; As[a_k + 5][a_r] = av1.y;
        As[a_k + 6][a_r] = av1.z; As[a_k + 7][a_r] = av1.w;
        *(float4*)&Bs[b_k][b_n] = bv0;
        *(float4*)&Bs[b_k][b_n + 4] = bv1;
        __syncthreads();

        #pragma unroll
        for (int kk = 0; kk < 16; kk++) {
            float a[8], b[8];
            *(float4*)(a)     = *(const float4*)&As[kk][ty * 4];
            *(float4*)(a + 4) = *(const float4*)&As[kk][ty * 4 + 64];
            *(float4*)(b)     = *(const float4*)&Bs[kk][tx * 4];
            *(float4*)(b + 4) = *(const float4*)&Bs[kk][tx * 4 + 64];
            #pragma unroll
            for (int i = 0; i < 8; i++)
                #pragma unroll
                for (int j = 0; j < 8; j++) acc[i][j] = fmaf(a[i], b[j], acc[i][j]);
        }
    }

    bool bf_path = (Cbf != nullptr) && (n0 == 0);
    #pragma unroll
    for (int i = 0; i < 8; i++) {
        int m = m0 + ty * 4 + (i & 3) + ((i >> 2) << 6);
        if (m < M) {
            if (bf_path) {
                unsigned short* cp = Cbf + (size_t)m * 128;
                ushort4 o0, o1;
                o0.x = f2bf(acc[i][0]); o0.y = f2bf(acc[i][1]);
                o0.z = f2bf(acc[i][2]); o0.w = f2bf(acc[i][3]);
                o1.x = f2bf(acc[i][4]); o1.y = f2bf(acc[i][5]);
                o1.z = f2bf(acc[i][6]); o1.w = f2bf(acc[i][7]);
                *(ushort4*)(cp + tx * 4) = o0;
                *(ushort4*)(cp + 64 + tx * 4) = o1;
            } else {
                float* cp = C + (size_t)m * ldc + (n0 - c_col_off);
                float4 v0 = make_float4(acc[i][0], acc[i][1], acc[i][2], acc[i][3]);
                float4 v1 = make_float4(acc[i][4], acc[i][5], acc[i][6], acc[i][7]);
                if (accumulate) {
                    float4 o0 = *(const float4*)(cp + tx * 4);
                    float4 o1 = *(const float4*)(cp + 64 + tx * 4);
                    v0.x += o0.x; v0.y += o0.y; v0.z += o0.z; v0.w += o0.w;
                    v1.x += o1.x; v1.y += o1.y; v1.z += o1.z; v1.w += o1.w;
                }
                *(float4*)(cp + tx * 4) = v0;
                *(float4*)(cp + 64 + tx * 4) = v1;
            }
        }
    }
}

// ---------------- concat two KxH weight matrices into Kx256 ----------------
__global__ __launch_bounds__(256) void wcat_kernel(const float* __restrict__ X, const float* __restrict__ Y,
                                                   float* __restrict__ W, int K) {
    int idx = blockIdx.x * 256 + threadIdx.x;
    if (idx < K * 256) {
        int k = idx >> 8;
        int n = idx & 255;
        W[idx] = (n < 128) ? X[k * 128 + n] : Y[k * 128 + n - 128];
    }
}

// ---------------- aggregation: mean of xb[src] (64 bf16 feats), 16 lanes/node ----------------
__global__ __launch_bounds__(256) void agg64_kernel(const unsigned short* __restrict__ xb, const int* __restrict__ row_ptr,
                                                    const int* __restrict__ col, const float* __restrict__ deg_inv,
                                                    float* __restrict__ aggx) {
    int tid = threadIdx.x;
    int g = tid >> 4;          // 16 nodes per block
    int f0 = (tid & 15) * 4;   // 4 feats per lane
    int i = blockIdx.x * 16 + g;
    if (i >= N_NODES) return;
    int s = row_ptr[i], e = row_ptr[i + 1];
    float a0 = 0.f, a1 = 0.f, a2 = 0.f, a3 = 0.f;
    for (int t = s; t < e; t++) {
        int j = col[t];
        ushort4 u = *(const ushort4*)(xb + (size_t)j * 64 + f0);
        a0 += bf2f(u.x); a1 += bf2f(u.y); a2 += bf2f(u.z); a3 += bf2f(u.w);
    }
    float di = deg_inv[i];
    float4 o = make_float4(a0 * di, a1 * di, a2 * di, a3 * di);
    *(float4*)(aggx + (size_t)i * 64 + f0) = o;
}

// ---------------- layers 2/3: h[i] = relu(deg_inv*sum Gl[j] + Gr[i] + b), 32 lanes/node ----------------
__global__ __launch_bounds__(256) void agg128_relu_kernel(const unsigned short* __restrict__ Gl, const float* __restrict__ Gr,
                                                          const int* __restrict__ row_ptr, const int* __restrict__ col,
                                                          const float* __restrict__ deg_inv, const float* __restrict__ bias,
                                                          float* __restrict__ h) {
    int tid = threadIdx.x;
    int g = tid >> 5;          // 8 nodes per block
    int f0 = (tid & 31) * 4;   // 4 feats per lane
    int i = blockIdx.x * 8 + g;
    if (i >= N_NODES) return;
    int s = row_ptr[i], e = row_ptr[i + 1];
    float a0 = 0.f, a1 = 0.f, a2 = 0.f, a3 = 0.f;
    int t = s;
    for (; t + 1 < e; t += 2) {
        int j0 = col[t], j1 = col[t + 1];
        ushort4 u0 = *(const ushort4*)(Gl + (size_t)j0 * 128 + f0);
        ushort4 u1 = *(const ushort4*)(Gl + (size_t)j1 * 128 + f0);
        a0 += bf2f(u0.x); a1 += bf2f(u0.y); a2 += bf2f(u0.z); a3 += bf2f(u0.w);
        a0 += bf2f(u1.x); a1 += bf2f(u1.y); a2 += bf2f(u1.z); a3 += bf2f(u1.w);
    }
    for (; t < e; t++) {
        int j = col[t];
        ushort4 u = *(const ushort4*)(Gl + (size_t)j * 128 + f0);
        a0 += bf2f(u.x); a1 += bf2f(u.y); a2 += bf2f(u.z); a3 += bf2f(u.w);
    }
    float di = deg_inv[i];
    float4 gr = *(const float4*)(Gr + (size_t)i * 128 + f0);
    float4 bs = *(const float4*)(bias + f0);
    float4 o;
    o.x = fmaxf(a0 * di + gr.x + bs.x, 0.f);
    o.y = fmaxf(a1 * di + gr.y + bs.y, 0.f);
    o.z = fmaxf(a2 * di + gr.z + bs.z, 0.f);
    o.w = fmaxf(a3 * di + gr.w + bs.w, 0.f);
    *(float4*)(h + (size_t)i * 128 + f0) = o;
}

// ---------------- layer1 epilogue ----------------
__global__ __launch_bounds__(256) void ln_kernel(const float* __restrict__ U, const float* __restrict__ b1,
                                                 const float* __restrict__ ln_g, const float* __restrict__ ln_b,
                                                 const float* __restrict__ bres, float* __restrict__ h) {
    int tid = threadIdx.x;
    int grp = tid >> 7;
    int f = tid & 127;
    int i = blockIdx.x * 2 + grp;
    bool valid = i < N_NODES;
    float t = 0.f;
    if (valid) t = U[(size_t)i * 256 + f] + b1[f];
    float s = t, s2 = t * t;
    #pragma unroll
    for (int off = 32; off; off >>= 1) {
        s += __shfl_down(s, off);
        s2 += __shfl_down(s2, off);
    }
    __shared__ float rs[4], rs2[4];
    int wave = tid >> 6;
    if ((tid & 63) == 0) { rs[wave] = s; rs2[wave] = s2; }
    __syncthreads();
    float sum = rs[grp * 2] + rs[grp * 2 + 1];
    float sumsq = rs2[grp * 2] + rs2[grp * 2 + 1];
    float mu = sum * (1.f / 128.f);
    float var = sumsq * (1.f / 128.f) - mu * mu;
    float r = rsqrtf(var + 1e-5f);
    if (valid) {
        float y = (t - mu) * r * ln_g[f] + ln_b[f];
        y = fmaxf(y, 0.f);
        y += U[(size_t)i * 256 + 128 + f] + bres[f];
        h[(size_t)i * 128 + f] = y;
    }
}

// ---------------- layer4 ----------------
__global__ __launch_bounds__(256) void pq_kernel(const float* __restrict__ h, const float* __restrict__ Wl4,
                                                 const float* __restrict__ Wr4, const float* __restrict__ b4,
                                                 float* __restrict__ p, float* __restrict__ q) {
    int tid = threadIdx.x;
    int lane = tid & 63;
    int w = tid >> 6;
    int i = blockIdx.x * 4 + w;
    if (i >= N_NODES) return;
    const float* hr = h + (size_t)i * 128;
    float a = hr[lane], b = hr[64 + lane];
    float pp = a * Wl4[lane] + b * Wl4[64 + lane];
    float qq = a * Wr4[lane] + b * Wr4[64 + lane];
    #pragma unroll
    for (int off = 32; off; off >>= 1) {
        pp += __shfl_down(pp, off);
        qq += __shfl_down(qq, off);
    }
    if (lane == 0) { p[i] = pp; q[i] = qq + b4[0]; }
}

__global__ __launch_bounds__(256) void final_kernel(const float* __restrict__ p, const float* __restrict__ q,
                                                    const int* __restrict__ row_ptr, const int* __restrict__ col,
                                                    const float* __restrict__ deg_inv, float* __restrict__ out) {
    int i = blockIdx.x * 256 + threadIdx.x;
    if (i >= N_NODES) return;
    int s = row_ptr[i], e = row_ptr[i + 1];
    float acc = 0.f;
    for (int t = s; t < e; t++) acc += p[col[t]];
    out[i] = acc * deg_inv[i] + q[i];
}

// ---------------- launch ----------------

extern "C" void kernel_launch(void* const* d_in, const int* in_sizes, int n_in,
                              void* d_out, int out_size, void* d_ws, size_t ws_size,
                              hipStream_t stream) {
    const float* x    = (const float*)d_in[0];
    const int*   ei   = (const int*)d_in[1];
    const float* Wl1  = (const float*)d_in[2];
    const float* Wr1  = (const float*)d_in[3];
    const float* b1   = (const float*)d_in[4];
    const float* ln_g = (const float*)d_in[5];
    const float* ln_b = (const float*)d_in[6];
    const float* Wres = (const float*)d_in[7];
    const float* bres = (const float*)d_in[8];
    const float* Wl2  = (const float*)d_in[9];
    const float* Wr2  = (const float*)d_in[10];
    const float* b2   = (const float*)d_in[11];
    const float* Wl3  = (const float*)d_in[12];
    const float* Wr3  = (const float*)d_in[13];
    const float* b3   = (const float*)d_in[14];
    const float* Wl4  = (const float*)d_in[15];
    const float* Wr4  = (const float*)d_in[16];
    const float* b4   = (const float*)d_in[17];
    float* out = (float*)d_out;

    char* w = (char*)d_ws;
    size_t off = 0;
    auto alloc = [&](size_t bytes) -> void* {
        off = (off + 255) & ~(size_t)255;
        void* pp = w + off;
        off += bytes;
        return pp;
    };

    int*   deg     = (int*)alloc(N_NODES * 4);
    int*   cnt     = (int*)alloc(N_NODES * 4);
    int*   row_ptr = (int*)alloc((N_NODES + 1) * 4);
    int*   bsum    = (int*)alloc(512);
    int*   col     = (int*)alloc(N_EDGES * 4);
    float* deg_inv = (float*)alloc(N_NODES * 4);
    float* Wcat    = (float*)alloc(128 * 256 * 4);
    unsigned short* xb = (unsigned short*)alloc((size_t)N_NODES * 64 * 2);
    float* aggx    = (float*)alloc((size_t)N_NODES * 64 * 4);
    float* U       = (float*)alloc((size_t)N_NODES * 256 * 4);
    float* h       = (float*)alloc((size_t)N_NODES * 128 * 4);
    float* p       = (float*)alloc(N_NODES * 4);
    float* q       = (float*)alloc(N_NODES * 4);
    // layers 2/3 outputs alias U (102.4 MB >= 25.6 + 51.2 MB)
    unsigned short* Gl = (unsigned short*)U;                       // N x 128 bf16
    float*          Gr = (float*)((char*)U + (size_t)N_NODES * 128 * 2 + 256);  // N x 128 fp32
    Gr = (float*)(((size_t)Gr + 255) & ~(size_t)255);
    (void)ws_size; (void)n_in; (void)in_sizes; (void)out_size;

    const int EB = (N_EDGES + 255) / 256;
    const int NB = (N_NODES + 255) / 256;
    const int SCB = (N_NODES + SCAN_ELEMS - 1) / SCAN_ELEMS;
    const int MB = (N_NODES + 127) / 128;

    // --- CSR build ---
    hipMemsetAsync(deg, 0, N_NODES * 4, stream);
    hipMemsetAsync(cnt, 0, N_NODES * 4, stream);
    count_deg_kernel<<<EB, 256, 0, stream>>>(ei, deg);
    scan_a_kernel<<<SCB, 256, 0, stream>>>(deg, bsum);
    scan_b_kernel<<<1, 64, 0, stream>>>(bsum, SCB);
    scan_c_kernel<<<SCB, 256, 0, stream>>>(deg, bsum, row_ptr);
    fill_csr_kernel<<<EB, 256, 0, stream>>>(ei, row_ptr, cnt, col);
    deginv_kernel<<<NB, 256, 0, stream>>>(deg, deg_inv);

    // --- layer 1 ---
    xbf_kernel<<<(N_NODES * IN_F / 4 + 255) / 256, 256, 0, stream>>>(x, xb);
    agg64_kernel<<<(N_NODES + 15) / 16, 256, 0, stream>>>(xb, row_ptr, col, deg_inv, aggx);
    wcat_kernel<<<64, 256, 0, stream>>>(Wr1, Wres, Wcat, 64);
    gemm_kernel<<<dim3(MB, 2), 256, 0, stream>>>(x, Wcat, U, nullptr, N_NODES, 64, 256, 256, 0, 0);
    gemm_kernel<<<dim3(MB, 1), 256, 0, stream>>>(aggx, Wl1, U, nullptr, N_NODES, 64, 128, 256, 0, 1);
    ln_kernel<<<(N_NODES + 1) / 2, 256, 0, stream>>>(U, b1, ln_g, ln_b, bres, h);

    // --- layer 2 ---
    wcat_kernel<<<128, 256, 0, stream>>>(Wl2, Wr2, Wcat, 128);
    gemm_kernel<<<dim3(MB, 2), 256, 0, stream>>>(h, Wcat, Gr, Gl, N_NODES, 128, 256, 128, 128, 0);
    agg128_relu_kernel<<<(N_NODES + 7) / 8, 256, 0, stream>>>(Gl, Gr, row_ptr, col, deg_inv, b2, h);

    // --- layer 3 ---
    wcat_kernel<<<128, 256, 0, stream>>>(Wl3, Wr3, Wcat, 128);
    gemm_kernel<<<dim3(MB, 2), 256, 0, stream>>>(h, Wcat, Gr, Gl, N_NODES, 128, 256, 128, 128, 0);
    agg128_relu_kernel<<<(N_NODES + 7) / 8, 256, 0, stream>>>(Gl, Gr, row_ptr, col, deg_inv, b3, h);

    // --- layer 4 ---
    pq_kernel<<<(N_NODES + 3) / 4, 256, 0, stream>>>(h, Wl4, Wr4, b4, p, q);
    final_kernel<<<NB, 256, 0, stream>>>(p, q, row_ptr, col, deg_inv, out);
}

// Round 3
// 648.896 us; speedup vs baseline: 1.4480x; 1.2526x over previous
//
#include <hip/hip_runtime.h>
#include <hip/hip_bf16.h>

#define N_NODES 100000
#define N_EDGES 1600000
#define IN_F 64
#define H_F 128

typedef __attribute__((ext_vector_type(8))) short short8v;
typedef __attribute__((ext_vector_type(4))) float float4v;

__device__ __forceinline__ unsigned short f2bf(float f) {
    unsigned int u = __float_as_uint(f);
    u = (u + 0x7FFFu + ((u >> 16) & 1u)) >> 16;   // RTNE
    return (unsigned short)u;
}
__device__ __forceinline__ float bf2f(unsigned short b) {
    return __uint_as_float((unsigned int)b << 16);
}

// ---------------- CSR build ----------------

__global__ __launch_bounds__(256) void count_deg_kernel(const int* __restrict__ ei, int* __restrict__ deg) {
    int e = blockIdx.x * 256 + threadIdx.x;
    if (e < N_EDGES) {
        int d = ei[N_EDGES + e];
        atomicAdd(&deg[d], 1);
    }
}

#define SCAN_ELEMS 1024
__global__ __launch_bounds__(256) void scan_a_kernel(const int* __restrict__ deg, int* __restrict__ bsum) {
    __shared__ int lds[256];
    int tid = threadIdx.x;
    int base = blockIdx.x * SCAN_ELEMS + tid * 4;
    int s = 0;
    #pragma unroll
    for (int i = 0; i < 4; i++) {
        int idx = base + i;
        s += (idx < N_NODES) ? deg[idx] : 0;
    }
    lds[tid] = s;
    __syncthreads();
    for (int off = 128; off; off >>= 1) {
        if (tid < off) lds[tid] += lds[tid + off];
        __syncthreads();
    }
    if (tid == 0) bsum[blockIdx.x] = lds[0];
}

__global__ void scan_b_kernel(int* __restrict__ bsum, int nb) {
    if (threadIdx.x == 0 && blockIdx.x == 0) {
        int acc = 0;
        for (int i = 0; i < nb; i++) { int v = bsum[i]; bsum[i] = acc; acc += v; }
    }
}

__global__ __launch_bounds__(256) void scan_c_kernel(const int* __restrict__ deg, const int* __restrict__ bsum,
                                                     int* __restrict__ row_ptr) {
    __shared__ int lds[256];
    int tid = threadIdx.x;
    int base = blockIdx.x * SCAN_ELEMS + tid * 4;
    int v[4];
    int s = 0;
    #pragma unroll
    for (int i = 0; i < 4; i++) {
        int idx = base + i;
        v[i] = (idx < N_NODES) ? deg[idx] : 0;
        s += v[i];
    }
    lds[tid] = s;
    __syncthreads();
    for (int off = 1; off < 256; off <<= 1) {
        int y = 0;
        if (tid >= off) y = lds[tid - off];
        __syncthreads();
        if (tid >= off) lds[tid] += y;
        __syncthreads();
    }
    int run = bsum[blockIdx.x] + lds[tid] - s;
    #pragma unroll
    for (int i = 0; i < 4; i++) {
        int idx = base + i;
        if (idx < N_NODES) row_ptr[idx] = run;
        run += v[i];
    }
    if (blockIdx.x == 0 && tid == 0) row_ptr[N_NODES] = N_EDGES;
}

__global__ __launch_bounds__(256) void fill_csr_kernel(const int* __restrict__ ei, const int* __restrict__ row_ptr,
                                                       int* __restrict__ cnt, int* __restrict__ col) {
    int e = blockIdx.x * 256 + threadIdx.x;
    if (e < N_EDGES) {
        int d = ei[N_EDGES + e];
        int pos = row_ptr[d] + atomicAdd(&cnt[d], 1);
        col[pos] = ei[e];
    }
}

__global__ __launch_bounds__(256) void deginv_kernel(const int* __restrict__ deg, float* __restrict__ deg_inv) {
    int i = blockIdx.x * 256 + threadIdx.x;
    if (i < N_NODES) deg_inv[i] = 1.0f / fmaxf((float)deg[i], 1.0f);
}

// ---------------- x (fp32 Nx64) -> xcat[:, 0:64] bf16 (ld 128) ----------------
__global__ __launch_bounds__(256) void xbf_kernel(const float* __restrict__ x, unsigned short* __restrict__ xcat) {
    int idx = blockIdx.x * 256 + threadIdx.x;   // one float4 per thread
    if (idx < N_NODES * IN_F / 4) {
        int node = idx >> 4;
        int f = (idx & 15) * 4;
        float4 v = *(const float4*)(x + (size_t)idx * 4);
        ushort4 o;
        o.x = f2bf(v.x); o.y = f2bf(v.y); o.z = f2bf(v.z); o.w = f2bf(v.w);
        *(ushort4*)(xcat + (size_t)node * 128 + f) = o;
    }
}

// ---------------- agg of x: mean into xcat[:, 64:128] bf16, 16 lanes/node ----------------
__global__ __launch_bounds__(256) void agg64_kernel(const unsigned short* __restrict__ xcat_in,
                                                    const int* __restrict__ row_ptr,
                                                    const int* __restrict__ col, const float* __restrict__ deg_inv,
                                                    unsigned short* __restrict__ xcat_out) {
    int tid = threadIdx.x;
    int g = tid >> 4;          // 16 nodes per block
    int f0 = (tid & 15) * 4;   // 4 feats per lane
    int i = blockIdx.x * 16 + g;
    if (i >= N_NODES) return;
    int s = row_ptr[i], e = row_ptr[i + 1];
    float a0 = 0.f, a1 = 0.f, a2 = 0.f, a3 = 0.f;
    for (int t = s; t < e; t++) {
        int j = col[t];
        ushort4 u = *(const ushort4*)(xcat_in + (size_t)j * 128 + f0);
        a0 += bf2f(u.x); a1 += bf2f(u.y); a2 += bf2f(u.z); a3 += bf2f(u.w);
    }
    float di = deg_inv[i];
    ushort4 o;
    o.x = f2bf(a0 * di); o.y = f2bf(a1 * di); o.z = f2bf(a2 * di); o.w = f2bf(a3 * di);
    *(ushort4*)(xcat_out + (size_t)i * 128 + 64 + f0) = o;
}

// ---------------- weight prep (transposed bf16) ----------------
// layer1: Bt[n][k], n in [0,256), k in [0,128):
//   n<128:  k<64 -> Wr1[k][n];      k>=64 -> Wl1[k-64][n]
//   n>=128: k<64 -> Wres[k][n-128]; k>=64 -> 0
__global__ __launch_bounds__(256) void wprep1_kernel(const float* __restrict__ Wr1, const float* __restrict__ Wl1,
                                                     const float* __restrict__ Wres, unsigned short* __restrict__ Bt) {
    int idx = blockIdx.x * 256 + threadIdx.x;   // n*128 + k
    if (idx >= 256 * 128) return;
    int n = idx >> 7;
    int k = idx & 127;
    float v;
    if (n < 128) v = (k < 64) ? Wr1[k * 128 + n] : Wl1[(k - 64) * 128 + n];
    else         v = (k < 64) ? Wres[k * 128 + (n - 128)] : 0.f;
    Bt[idx] = f2bf(v);
}

// layers 2/3: Bt[n][k] = (n<128 ? Wl[k][n] : Wr[k][n-128])
__global__ __launch_bounds__(256) void wprep23_kernel(const float* __restrict__ Wl, const float* __restrict__ Wr,
                                                      unsigned short* __restrict__ Bt) {
    int idx = blockIdx.x * 256 + threadIdx.x;
    if (idx >= 256 * 128) return;
    int n = idx >> 7;
    int k = idx & 127;
    float v = (n < 128) ? Wl[k * 128 + n] : Wr[k * 128 + (n - 128)];
    Bt[idx] = f2bf(v);
}

// ---------------- MFMA bf16 GEMM: C[M x 256] = A[M x 128] @ Bt^T ----------------
// A row-major bf16 ld=128; Bt is [256][128] bf16 (B transposed). 128x128 tile per
// block, 4 waves in 2x2 of 64x64, 16x16x32 MFMA, BK=64 two-phase LDS staging.
// Epilogue: if Cbf != null and blockIdx.y==0 -> bf16 store ld 128;
// else fp32 store to Cf + m*ldc + (n0 - c_col_off).
#define LP 72   // padded LDS row length in shorts (64 + 8)

__global__ __launch_bounds__(256) void mgemm_kernel(const unsigned short* __restrict__ A,
                                                    const unsigned short* __restrict__ Bt, int M,
                                                    float* __restrict__ Cf, int ldc, int c_col_off,
                                                    unsigned short* __restrict__ Cbf) {
    __shared__ unsigned short As[128 * LP];
    __shared__ unsigned short Bs[128 * LP];
    int tid = threadIdx.x;
    int m0 = blockIdx.x * 128;
    int n0 = blockIdx.y * 128;

    int lane = tid & 63;
    int wave = tid >> 6;
    int wm = (wave & 1) * 64;
    int wn = (wave >> 1) * 64;
    int lm = lane & 15;
    int lk = (lane >> 4) * 8;

    float4v acc[4][4];
    #pragma unroll
    for (int i = 0; i < 4; i++)
        #pragma unroll
        for (int j = 0; j < 4; j++) acc[i][j] = (float4v)0.f;

    int sr = tid >> 3;          // staging row 0..31
    int sc = (tid & 7) * 8;     // staging col (shorts)

    for (int ks = 0; ks < 128; ks += 64) {
        if (ks) __syncthreads();
        #pragma unroll
        for (int rr = 0; rr < 128; rr += 32) {
            int r = sr + rr;
            int gm = m0 + r; if (gm > M - 1) gm = M - 1;
            ulonglong2 va = *(const ulonglong2*)(A + (size_t)gm * 128 + ks + sc);
            *(ulonglong2*)&As[r * LP + sc] = va;
            ulonglong2 vb = *(const ulonglong2*)(Bt + (size_t)(n0 + r) * 128 + ks + sc);
            *(ulonglong2*)&Bs[r * LP + sc] = vb;
        }
        __syncthreads();

        #pragma unroll
        for (int k0 = 0; k0 < 64; k0 += 32) {
            short8v af[4], bf[4];
            #pragma unroll
            for (int i = 0; i < 4; i++)
                af[i] = *(const short8v*)&As[(wm + i * 16 + lm) * LP + k0 + lk];
            #pragma unroll
            for (int j = 0; j < 4; j++)
                bf[j] = *(const short8v*)&Bs[(wn + j * 16 + lm) * LP + k0 + lk];
            #pragma unroll
            for (int i = 0; i < 4; i++)
                #pragma unroll
                for (int j = 0; j < 4; j++)
                    acc[i][j] = __builtin_amdgcn_mfma_f32_16x16x32_bf16(af[i], bf[j], acc[i][j], 0, 0, 0);
        }
    }

    bool bf_path = (Cbf != nullptr) && (blockIdx.y == 0);
    int r0b = (lane >> 4) * 4;
    #pragma unroll
    for (int i = 0; i < 4; i++) {
        #pragma unroll
        for (int j = 0; j < 4; j++) {
            int cc = wn + j * 16 + (lane & 15);
            #pragma unroll
            for (int r = 0; r < 4; r++) {
                int m = m0 + wm + i * 16 + r0b + r;
                if (m < M) {
                    if (bf_path) Cbf[(size_t)m * 128 + cc] = f2bf(acc[i][j][r]);
                    else         Cf[(size_t)m * ldc + (n0 - c_col_off) + cc] = acc[i][j][r];
                }
            }
        }
    }
}

// ---------------- layers 2/3 epilogue+agg: h = relu(deg_inv*sum Gl[j] + Gr[i] + b) -> bf16 ----------------
__global__ __launch_bounds__(256) void agg128_relu_kernel(const unsigned short* __restrict__ Gl, const float* __restrict__ Gr,
                                                          const int* __restrict__ row_ptr, const int* __restrict__ col,
                                                          const float* __restrict__ deg_inv, const float* __restrict__ bias,
                                                          unsigned short* __restrict__ hb) {
    int tid = threadIdx.x;
    int g = tid >> 5;          // 8 nodes per block
    int f0 = (tid & 31) * 4;   // 4 feats per lane
    int i = blockIdx.x * 8 + g;
    if (i >= N_NODES) return;
    int s = row_ptr[i], e = row_ptr[i + 1];
    float a0 = 0.f, a1 = 0.f, a2 = 0.f, a3 = 0.f;
    int t = s;
    for (; t + 1 < e; t += 2) {
        int j0 = col[t], j1 = col[t + 1];
        ushort4 u0 = *(const ushort4*)(Gl + (size_t)j0 * 128 + f0);
        ushort4 u1 = *(const ushort4*)(Gl + (size_t)j1 * 128 + f0);
        a0 += bf2f(u0.x); a1 += bf2f(u0.y); a2 += bf2f(u0.z); a3 += bf2f(u0.w);
        a0 += bf2f(u1.x); a1 += bf2f(u1.y); a2 += bf2f(u1.z); a3 += bf2f(u1.w);
    }
    for (; t < e; t++) {
        int j = col[t];
        ushort4 u = *(const ushort4*)(Gl + (size_t)j * 128 + f0);
        a0 += bf2f(u.x); a1 += bf2f(u.y); a2 += bf2f(u.z); a3 += bf2f(u.w);
    }
    float di = deg_inv[i];
    float4 gr = *(const float4*)(Gr + (size_t)i * 128 + f0);
    float4 bs = *(const float4*)(bias + f0);
    ushort4 o;
    o.x = f2bf(fmaxf(a0 * di + gr.x + bs.x, 0.f));
    o.y = f2bf(fmaxf(a1 * di + gr.y + bs.y, 0.f));
    o.z = f2bf(fmaxf(a2 * di + gr.z + bs.z, 0.f));
    o.w = f2bf(fmaxf(a3 * di + gr.w + bs.w, 0.f));
    *(ushort4*)(hb + (size_t)i * 128 + f0) = o;
}

// ---------------- layer1 epilogue: t=U[:,0:128]+b1 -> LN -> relu -> + U[:,128:256]+bres -> bf16 ----------------
__global__ __launch_bounds__(256) void ln_kernel(const float* __restrict__ U, const float* __restrict__ b1,
                                                 const float* __restrict__ ln_g, const float* __restrict__ ln_b,
                                                 const float* __restrict__ bres, unsigned short* __restrict__ hb) {
    int tid = threadIdx.x;
    int grp = tid >> 7;
    int f = tid & 127;
    int i = blockIdx.x * 2 + grp;
    bool valid = i < N_NODES;
    float t = 0.f;
    if (valid) t = U[(size_t)i * 256 + f] + b1[f];
    float s = t, s2 = t * t;
    #pragma unroll
    for (int off = 32; off; off >>= 1) {
        s += __shfl_down(s, off);
        s2 += __shfl_down(s2, off);
    }
    __shared__ float rs[4], rs2[4];
    int wave = tid >> 6;
    if ((tid & 63) == 0) { rs[wave] = s; rs2[wave] = s2; }
    __syncthreads();
    float sum = rs[grp * 2] + rs[grp * 2 + 1];
    float sumsq = rs2[grp * 2] + rs2[grp * 2 + 1];
    float mu = sum * (1.f / 128.f);
    float var = sumsq * (1.f / 128.f) - mu * mu;
    float r = rsqrtf(var + 1e-5f);
    if (valid) {
        float y = (t - mu) * r * ln_g[f] + ln_b[f];
        y = fmaxf(y, 0.f);
        y += U[(size_t)i * 256 + 128 + f] + bres[f];
        hb[(size_t)i * 128 + f] = f2bf(y);
    }
}

// ---------------- layer4 ----------------
__global__ __launch_bounds__(256) void pq_kernel(const unsigned short* __restrict__ hb, const float* __restrict__ Wl4,
                                                 const float* __restrict__ Wr4, const float* __restrict__ b4,
                                                 float* __restrict__ p, float* __restrict__ q) {
    int tid = threadIdx.x;
    int lane = tid & 63;
    int w = tid >> 6;
    int i = blockIdx.x * 4 + w;
    if (i >= N_NODES) return;
    const unsigned short* hr = hb + (size_t)i * 128;
    float a = bf2f(hr[lane]), b = bf2f(hr[64 + lane]);
    float pp = a * Wl4[lane] + b * Wl4[64 + lane];
    float qq = a * Wr4[lane] + b * Wr4[64 + lane];
    #pragma unroll
    for (int off = 32; off; off >>= 1) {
        pp += __shfl_down(pp, off);
        qq += __shfl_down(qq, off);
    }
    if (lane == 0) { p[i] = pp; q[i] = qq + b4[0]; }
}

__global__ __launch_bounds__(256) void final_kernel(const float* __restrict__ p, const float* __restrict__ q,
                                                    const int* __restrict__ row_ptr, const int* __restrict__ col,
                                                    const float* __restrict__ deg_inv, float* __restrict__ out) {
    int i = blockIdx.x * 256 + threadIdx.x;
    if (i >= N_NODES) return;
    int s = row_ptr[i], e = row_ptr[i + 1];
    float acc = 0.f;
    for (int t = s; t < e; t++) acc += p[col[t]];
    out[i] = acc * deg_inv[i] + q[i];
}

// ---------------- launch ----------------

extern "C" void kernel_launch(void* const* d_in, const int* in_sizes, int n_in,
                              void* d_out, int out_size, void* d_ws, size_t ws_size,
                              hipStream_t stream) {
    const float* x    = (const float*)d_in[0];
    const int*   ei   = (const int*)d_in[1];
    const float* Wl1  = (const float*)d_in[2];
    const float* Wr1  = (const float*)d_in[3];
    const float* b1   = (const float*)d_in[4];
    const float* ln_g = (const float*)d_in[5];
    const float* ln_b = (const float*)d_in[6];
    const float* Wres = (const float*)d_in[7];
    const float* bres = (const float*)d_in[8];
    const float* Wl2  = (const float*)d_in[9];
    const float* Wr2  = (const float*)d_in[10];
    const float* b2   = (const float*)d_in[11];
    const float* Wl3  = (const float*)d_in[12];
    const float* Wr3  = (const float*)d_in[13];
    const float* b3   = (const float*)d_in[14];
    const float* Wl4  = (const float*)d_in[15];
    const float* Wr4  = (const float*)d_in[16];
    const float* b4   = (const float*)d_in[17];
    float* out = (float*)d_out;

    char* w = (char*)d_ws;
    size_t off = 0;
    auto alloc = [&](size_t bytes) -> void* {
        off = (off + 255) & ~(size_t)255;
        void* pp = w + off;
        off += bytes;
        return pp;
    };

    int*   deg     = (int*)alloc(N_NODES * 4);
    int*   cnt     = (int*)alloc(N_NODES * 4);
    int*   row_ptr = (int*)alloc((N_NODES + 1) * 4);
    int*   bsum    = (int*)alloc(512);
    int*   col     = (int*)alloc(N_EDGES * 4);
    float* deg_inv = (float*)alloc(N_NODES * 4);
    unsigned short* Btw  = (unsigned short*)alloc(256 * 128 * 2);
    unsigned short* xcat = (unsigned short*)alloc((size_t)N_NODES * 128 * 2);
    unsigned short* hb   = (unsigned short*)alloc((size_t)N_NODES * 128 * 2);
    float* U       = (float*)alloc((size_t)N_NODES * 256 * 4);
    float* p       = (float*)alloc(N_NODES * 4);
    float* q       = (float*)alloc(N_NODES * 4);
    // layers 2/3 GEMM outputs alias U (102.4 MB >= 25.6 + 51.2 MB)
    unsigned short* Gl = (unsigned short*)U;                                    // N x 128 bf16
    float*          Gr = (float*)(((size_t)((char*)U + (size_t)N_NODES * 128 * 2) + 255) & ~(size_t)255);
    (void)ws_size; (void)n_in; (void)in_sizes; (void)out_size;

    const int EB = (N_EDGES + 255) / 256;
    const int NB = (N_NODES + 255) / 256;
    const int SCB = (N_NODES + SCAN_ELEMS - 1) / SCAN_ELEMS;
    const int MB = (N_NODES + 127) / 128;   // 782

    // --- CSR build ---
    hipMemsetAsync(deg, 0, N_NODES * 4, stream);
    hipMemsetAsync(cnt, 0, N_NODES * 4, stream);
    count_deg_kernel<<<EB, 256, 0, stream>>>(ei, deg);
    scan_a_kernel<<<SCB, 256, 0, stream>>>(deg, bsum);
    scan_b_kernel<<<1, 64, 0, stream>>>(bsum, SCB);
    scan_c_kernel<<<SCB, 256, 0, stream>>>(deg, bsum, row_ptr);
    fill_csr_kernel<<<EB, 256, 0, stream>>>(ei, row_ptr, cnt, col);
    deginv_kernel<<<NB, 256, 0, stream>>>(deg, deg_inv);

    // --- layer 1: A = [x | mean-agg(x)] bf16, B = [[Wr1|Wres],[Wl1|0]] ---
    xbf_kernel<<<(N_NODES * IN_F / 4 + 255) / 256, 256, 0, stream>>>(x, xcat);
    agg64_kernel<<<(N_NODES + 15) / 16, 256, 0, stream>>>(xcat, row_ptr, col, deg_inv, xcat);
    wprep1_kernel<<<128, 256, 0, stream>>>(Wr1, Wl1, Wres, Btw);
    mgemm_kernel<<<dim3(MB, 2), 256, 0, stream>>>(xcat, Btw, N_NODES, U, 256, 0, nullptr);
    ln_kernel<<<(N_NODES + 1) / 2, 256, 0, stream>>>(U, b1, ln_g, ln_b, bres, hb);

    // --- layer 2 ---
    wprep23_kernel<<<128, 256, 0, stream>>>(Wl2, Wr2, Btw);
    mgemm_kernel<<<dim3(MB, 2), 256, 0, stream>>>(hb, Btw, N_NODES, Gr, 128, 128, Gl);
    agg128_relu_kernel<<<(N_NODES + 7) / 8, 256, 0, stream>>>(Gl, Gr, row_ptr, col, deg_inv, b2, hb);

    // --- layer 3 ---
    wprep23_kernel<<<128, 256, 0, stream>>>(Wl3, Wr3, Btw);
    mgemm_kernel<<<dim3(MB, 2), 256, 0, stream>>>(hb, Btw, N_NODES, Gr, 128, 128, Gl);
    agg128_relu_kernel<<<(N_NODES + 7) / 8, 256, 0, stream>>>(Gl, Gr, row_ptr, col, deg_inv, b3, hb);

    // --- layer 4 ---
    pq_kernel<<<(N_NODES + 3) / 4, 256, 0, stream>>>(hb, Wl4, Wr4, b4, p, q);
    final_kernel<<<NB, 256, 0, stream>>>(p, q, row_ptr, col, deg_inv, out);
}

// Round 4
// 568.234 us; speedup vs baseline: 1.6536x; 1.1420x over previous
//
#include <hip/hip_runtime.h>
#include <hip/hip_bf16.h>

#define N_NODES 100000
#define N_EDGES 1600000
#define IN_F 64
#define H_F 128

#define NBKT 782                 // ceil(N_NODES / 128)
#define BKT_CHUNK 13334          // ceil(N_EDGES / 120)
#define SCAT_BLOCKS 120

typedef __attribute__((ext_vector_type(8))) short short8v;
typedef __attribute__((ext_vector_type(4))) float float4v;

__device__ __forceinline__ unsigned short f2bf(float f) {
    unsigned int u = __float_as_uint(f);
    u = (u + 0x7FFFu + ((u >> 16) & 1u)) >> 16;   // RTNE
    return (unsigned short)u;
}
__device__ __forceinline__ float bf2f(unsigned short b) {
    return __uint_as_float((unsigned int)b << 16);
}

// ---------------- CSR build via 2-level bucket counting sort ----------------
// bucket b = dst ids [b*128, b*128+128)

// S1: global bucket histogram (per-block LDS hist, then one atomic per bucket)
__global__ __launch_bounds__(256) void bkt_count_kernel(const int* __restrict__ ei, int* __restrict__ bucket_cnt) {
    __shared__ int h[NBKT];
    int tid = threadIdx.x;
    for (int i = tid; i < NBKT; i += 256) h[i] = 0;
    __syncthreads();
    int start = blockIdx.x * BKT_CHUNK;
    int end = start + BKT_CHUNK; if (end > N_EDGES) end = N_EDGES;
    for (int i = start + tid; i < end; i += 256) {
        int d = ei[N_EDGES + i];
        atomicAdd(&h[d >> 7], 1);
    }
    __syncthreads();
    for (int i = tid; i < NBKT; i += 256) {
        int c = h[i];
        if (c) atomicAdd(&bucket_cnt[i], c);
    }
}

// S2: exclusive scan of 782 bucket counts -> bucket_off, cursor
__global__ __launch_bounds__(256) void bkt_scan_kernel(const int* __restrict__ bucket_cnt,
                                                       int* __restrict__ bucket_off, int* __restrict__ cursor) {
    __shared__ int ps[256];
    int tid = threadIdx.x;
    int base = tid * 4;
    int v[4];
    int s = 0;
    #pragma unroll
    for (int i = 0; i < 4; i++) {
        v[i] = (base + i < NBKT) ? bucket_cnt[base + i] : 0;
        s += v[i];
    }
    ps[tid] = s;
    __syncthreads();
    for (int off = 1; off < 256; off <<= 1) {
        int y = 0;
        if (tid >= off) y = ps[tid - off];
        __syncthreads();
        if (tid >= off) ps[tid] += y;
        __syncthreads();
    }
    int run = ps[tid] - s;   // exclusive
    #pragma unroll
    for (int i = 0; i < 4; i++) {
        if (base + i < NBKT) { bucket_off[base + i] = run; cursor[base + i] = run; }
        run += v[i];
    }
    if (tid == 0) bucket_off[NBKT] = N_EDGES;
}

// S3: scatter (src,dst) pairs into bucket-ordered array; per-block range reservation
__global__ __launch_bounds__(256) void bkt_scatter_kernel(const int* __restrict__ ei, int* __restrict__ cursor,
                                                          int2* __restrict__ pairs) {
    __shared__ int h[NBKT];
    __shared__ int basearr[NBKT];
    int tid = threadIdx.x;
    for (int i = tid; i < NBKT; i += 256) h[i] = 0;
    __syncthreads();
    int start = blockIdx.x * BKT_CHUNK;
    int end = start + BKT_CHUNK; if (end > N_EDGES) end = N_EDGES;
    for (int i = start + tid; i < end; i += 256) {
        int d = ei[N_EDGES + i];
        atomicAdd(&h[d >> 7], 1);
    }
    __syncthreads();
    for (int b = tid; b < NBKT; b += 256) {
        int c = h[b];
        basearr[b] = c ? atomicAdd(&cursor[b], c) : 0;
        h[b] = 0;
    }
    __syncthreads();
    for (int i = start + tid; i < end; i += 256) {
        int s = ei[i];
        int d = ei[N_EDGES + i];
        int bkt = d >> 7;
        int pos = basearr[bkt] + atomicAdd(&h[bkt], 1);
        pairs[pos] = make_int2(s, d);
    }
}

// S4: per-bucket degree count (localized LDS atomics, coalesced deg write)
__global__ __launch_bounds__(256) void bkt_deg_kernel(const int2* __restrict__ pairs, const int* __restrict__ bucket_off,
                                                      int* __restrict__ deg) {
    __shared__ int c[128];
    int tid = threadIdx.x;
    if (tid < 128) c[tid] = 0;
    __syncthreads();
    int s0 = bucket_off[blockIdx.x], s1 = bucket_off[blockIdx.x + 1];
    for (int i = s0 + tid; i < s1; i += 256) {
        int d = pairs[i].y;
        atomicAdd(&c[d & 127], 1);
    }
    __syncthreads();
    int node = blockIdx.x * 128 + tid;
    if (tid < 128 && node < N_NODES) deg[node] = c[tid];
}

// S5: per-bucket CSR fill — writes land in this bucket's contiguous col window
__global__ __launch_bounds__(256) void bkt_fill_kernel(const int2* __restrict__ pairs, const int* __restrict__ bucket_off,
                                                       const int* __restrict__ row_ptr, int* __restrict__ col) {
    __shared__ int rp[128];
    __shared__ int c[128];
    int tid = threadIdx.x;
    int node = blockIdx.x * 128 + tid;
    if (tid < 128) {
        rp[tid] = (node < N_NODES) ? row_ptr[node] : 0;
        c[tid] = 0;
    }
    __syncthreads();
    int s0 = bucket_off[blockIdx.x], s1 = bucket_off[blockIdx.x + 1];
    for (int i = s0 + tid; i < s1; i += 256) {
        int2 e = pairs[i];
        int dl = e.y & 127;
        int pos = rp[dl] + atomicAdd(&c[dl], 1);
        col[pos] = e.x;
    }
}

// ---------------- scan of deg -> row_ptr ----------------
#define SCAN_ELEMS 1024
__global__ __launch_bounds__(256) void scan_a_kernel(const int* __restrict__ deg, int* __restrict__ bsum) {
    __shared__ int lds[256];
    int tid = threadIdx.x;
    int base = blockIdx.x * SCAN_ELEMS + tid * 4;
    int s = 0;
    #pragma unroll
    for (int i = 0; i < 4; i++) {
        int idx = base + i;
        s += (idx < N_NODES) ? deg[idx] : 0;
    }
    lds[tid] = s;
    __syncthreads();
    for (int off = 128; off; off >>= 1) {
        if (tid < off) lds[tid] += lds[tid + off];
        __syncthreads();
    }
    if (tid == 0) bsum[blockIdx.x] = lds[0];
}

__global__ void scan_b_kernel(int* __restrict__ bsum, int nb) {
    if (threadIdx.x == 0 && blockIdx.x == 0) {
        int acc = 0;
        for (int i = 0; i < nb; i++) { int v = bsum[i]; bsum[i] = acc; acc += v; }
    }
}

__global__ __launch_bounds__(256) void scan_c_kernel(const int* __restrict__ deg, const int* __restrict__ bsum,
                                                     int* __restrict__ row_ptr) {
    __shared__ int lds[256];
    int tid = threadIdx.x;
    int base = blockIdx.x * SCAN_ELEMS + tid * 4;
    int v[4];
    int s = 0;
    #pragma unroll
    for (int i = 0; i < 4; i++) {
        int idx = base + i;
        v[i] = (idx < N_NODES) ? deg[idx] : 0;
        s += v[i];
    }
    lds[tid] = s;
    __syncthreads();
    for (int off = 1; off < 256; off <<= 1) {
        int y = 0;
        if (tid >= off) y = lds[tid - off];
        __syncthreads();
        if (tid >= off) lds[tid] += y;
        __syncthreads();
    }
    int run = bsum[blockIdx.x] + lds[tid] - s;
    #pragma unroll
    for (int i = 0; i < 4; i++) {
        int idx = base + i;
        if (idx < N_NODES) row_ptr[idx] = run;
        run += v[i];
    }
    if (blockIdx.x == 0 && tid == 0) row_ptr[N_NODES] = N_EDGES;
}

__global__ __launch_bounds__(256) void deginv_kernel(const int* __restrict__ deg, float* __restrict__ deg_inv) {
    int i = blockIdx.x * 256 + threadIdx.x;
    if (i < N_NODES) deg_inv[i] = 1.0f / fmaxf((float)deg[i], 1.0f);
}

// ---------------- x (fp32 Nx64) -> xcat[:, 0:64] bf16 (ld 128) ----------------
__global__ __launch_bounds__(256) void xbf_kernel(const float* __restrict__ x, unsigned short* __restrict__ xcat) {
    int idx = blockIdx.x * 256 + threadIdx.x;   // one float4 per thread
    if (idx < N_NODES * IN_F / 4) {
        int node = idx >> 4;
        int f = (idx & 15) * 4;
        float4 v = *(const float4*)(x + (size_t)idx * 4);
        ushort4 o;
        o.x = f2bf(v.x); o.y = f2bf(v.y); o.z = f2bf(v.z); o.w = f2bf(v.w);
        *(ushort4*)(xcat + (size_t)node * 128 + f) = o;
    }
}

// ---------------- agg of x: mean into xcat[:, 64:128] bf16, 16 lanes/node ----------------
__global__ __launch_bounds__(256) void agg64_kernel(const unsigned short* __restrict__ xcat_in,
                                                    const int* __restrict__ row_ptr,
                                                    const int* __restrict__ col, const float* __restrict__ deg_inv,
                                                    unsigned short* __restrict__ xcat_out) {
    int tid = threadIdx.x;
    int g = tid >> 4;          // 16 nodes per block
    int f0 = (tid & 15) * 4;   // 4 feats per lane
    int i = blockIdx.x * 16 + g;
    if (i >= N_NODES) return;
    int s = row_ptr[i], e = row_ptr[i + 1];
    float a0 = 0.f, a1 = 0.f, a2 = 0.f, a3 = 0.f;
    for (int t = s; t < e; t++) {
        int j = col[t];
        ushort4 u = *(const ushort4*)(xcat_in + (size_t)j * 128 + f0);
        a0 += bf2f(u.x); a1 += bf2f(u.y); a2 += bf2f(u.z); a3 += bf2f(u.w);
    }
    float di = deg_inv[i];
    ushort4 o;
    o.x = f2bf(a0 * di); o.y = f2bf(a1 * di); o.z = f2bf(a2 * di); o.w = f2bf(a3 * di);
    *(ushort4*)(xcat_out + (size_t)i * 128 + 64 + f0) = o;
}

// ---------------- weight prep (transposed bf16) ----------------
__global__ __launch_bounds__(256) void wprep1_kernel(const float* __restrict__ Wr1, const float* __restrict__ Wl1,
                                                     const float* __restrict__ Wres, unsigned short* __restrict__ Bt) {
    int idx = blockIdx.x * 256 + threadIdx.x;   // n*128 + k
    if (idx >= 256 * 128) return;
    int n = idx >> 7;
    int k = idx & 127;
    float v;
    if (n < 128) v = (k < 64) ? Wr1[k * 128 + n] : Wl1[(k - 64) * 128 + n];
    else         v = (k < 64) ? Wres[k * 128 + (n - 128)] : 0.f;
    Bt[idx] = f2bf(v);
}

__global__ __launch_bounds__(256) void wprep23_kernel(const float* __restrict__ Wl, const float* __restrict__ Wr,
                                                      unsigned short* __restrict__ Bt) {
    int idx = blockIdx.x * 256 + threadIdx.x;
    if (idx >= 256 * 128) return;
    int n = idx >> 7;
    int k = idx & 127;
    float v = (n < 128) ? Wl[k * 128 + n] : Wr[k * 128 + (n - 128)];
    Bt[idx] = f2bf(v);
}

// ---------------- MFMA bf16 GEMM: C[M x 256] = A[M x 128] @ Bt^T ----------------
#define LP 72   // padded LDS row length in shorts (64 + 8)

__global__ __launch_bounds__(256) void mgemm_kernel(const unsigned short* __restrict__ A,
                                                    const unsigned short* __restrict__ Bt, int M,
                                                    float* __restrict__ Cf, int ldc, int c_col_off,
                                                    unsigned short* __restrict__ Cbf) {
    __shared__ unsigned short As[128 * LP];
    __shared__ unsigned short Bs[128 * LP];
    int tid = threadIdx.x;
    int m0 = blockIdx.x * 128;
    int n0 = blockIdx.y * 128;

    int lane = tid & 63;
    int wave = tid >> 6;
    int wm = (wave & 1) * 64;
    int wn = (wave >> 1) * 64;
    int lm = lane & 15;
    int lk = (lane >> 4) * 8;

    float4v acc[4][4];
    #pragma unroll
    for (int i = 0; i < 4; i++)
        #pragma unroll
        for (int j = 0; j < 4; j++) acc[i][j] = (float4v)0.f;

    int sr = tid >> 3;          // staging row 0..31
    int sc = (tid & 7) * 8;     // staging col (shorts)

    for (int ks = 0; ks < 128; ks += 64) {
        if (ks) __syncthreads();
        #pragma unroll
        for (int rr = 0; rr < 128; rr += 32) {
            int r = sr + rr;
            int gm = m0 + r; if (gm > M - 1) gm = M - 1;
            ulonglong2 va = *(const ulonglong2*)(A + (size_t)gm * 128 + ks + sc);
            *(ulonglong2*)&As[r * LP + sc] = va;
            ulonglong2 vb = *(const ulonglong2*)(Bt + (size_t)(n0 + r) * 128 + ks + sc);
            *(ulonglong2*)&Bs[r * LP + sc] = vb;
        }
        __syncthreads();

        #pragma unroll
        for (int k0 = 0; k0 < 64; k0 += 32) {
            short8v af[4], bf[4];
            #pragma unroll
            for (int i = 0; i < 4; i++)
                af[i] = *(const short8v*)&As[(wm + i * 16 + lm) * LP + k0 + lk];
            #pragma unroll
            for (int j = 0; j < 4; j++)
                bf[j] = *(const short8v*)&Bs[(wn + j * 16 + lm) * LP + k0 + lk];
            #pragma unroll
            for (int i = 0; i < 4; i++)
                #pragma unroll
                for (int j = 0; j < 4; j++)
                    acc[i][j] = __builtin_amdgcn_mfma_f32_16x16x32_bf16(af[i], bf[j], acc[i][j], 0, 0, 0);
        }
    }

    bool bf_path = (Cbf != nullptr) && (blockIdx.y == 0);
    int r0b = (lane >> 4) * 4;
    #pragma unroll
    for (int i = 0; i < 4; i++) {
        #pragma unroll
        for (int j = 0; j < 4; j++) {
            int cc = wn + j * 16 + (lane & 15);
            #pragma unroll
            for (int r = 0; r < 4; r++) {
                int m = m0 + wm + i * 16 + r0b + r;
                if (m < M) {
                    if (bf_path) Cbf[(size_t)m * 128 + cc] = f2bf(acc[i][j][r]);
                    else         Cf[(size_t)m * ldc + (n0 - c_col_off) + cc] = acc[i][j][r];
                }
            }
        }
    }
}

// ---------------- layers 2/3 epilogue+agg ----------------
__global__ __launch_bounds__(256) void agg128_relu_kernel(const unsigned short* __restrict__ Gl, const float* __restrict__ Gr,
                                                          const int* __restrict__ row_ptr, const int* __restrict__ col,
                                                          const float* __restrict__ deg_inv, const float* __restrict__ bias,
                                                          unsigned short* __restrict__ hb) {
    int tid = threadIdx.x;
    int g = tid >> 5;          // 8 nodes per block
    int f0 = (tid & 31) * 4;   // 4 feats per lane
    int i = blockIdx.x * 8 + g;
    if (i >= N_NODES) return;
    int s = row_ptr[i], e = row_ptr[i + 1];
    float a0 = 0.f, a1 = 0.f, a2 = 0.f, a3 = 0.f;
    int t = s;
    for (; t + 1 < e; t += 2) {
        int j0 = col[t], j1 = col[t + 1];
        ushort4 u0 = *(const ushort4*)(Gl + (size_t)j0 * 128 + f0);
        ushort4 u1 = *(const ushort4*)(Gl + (size_t)j1 * 128 + f0);
        a0 += bf2f(u0.x); a1 += bf2f(u0.y); a2 += bf2f(u0.z); a3 += bf2f(u0.w);
        a0 += bf2f(u1.x); a1 += bf2f(u1.y); a2 += bf2f(u1.z); a3 += bf2f(u1.w);
    }
    for (; t < e; t++) {
        int j = col[t];
        ushort4 u = *(const ushort4*)(Gl + (size_t)j * 128 + f0);
        a0 += bf2f(u.x); a1 += bf2f(u.y); a2 += bf2f(u.z); a3 += bf2f(u.w);
    }
    float di = deg_inv[i];
    float4 gr = *(const float4*)(Gr + (size_t)i * 128 + f0);
    float4 bs = *(const float4*)(bias + f0);
    ushort4 o;
    o.x = f2bf(fmaxf(a0 * di + gr.x + bs.x, 0.f));
    o.y = f2bf(fmaxf(a1 * di + gr.y + bs.y, 0.f));
    o.z = f2bf(fmaxf(a2 * di + gr.z + bs.z, 0.f));
    o.w = f2bf(fmaxf(a3 * di + gr.w + bs.w, 0.f));
    *(ushort4*)(hb + (size_t)i * 128 + f0) = o;
}

// ---------------- layer1 epilogue ----------------
__global__ __launch_bounds__(256) void ln_kernel(const float* __restrict__ U, const float* __restrict__ b1,
                                                 const float* __restrict__ ln_g, const float* __restrict__ ln_b,
                                                 const float* __restrict__ bres, unsigned short* __restrict__ hb) {
    int tid = threadIdx.x;
    int grp = tid >> 7;
    int f = tid & 127;
    int i = blockIdx.x * 2 + grp;
    bool valid = i < N_NODES;
    float t = 0.f;
    if (valid) t = U[(size_t)i * 256 + f] + b1[f];
    float s = t, s2 = t * t;
    #pragma unroll
    for (int off = 32; off; off >>= 1) {
        s += __shfl_down(s, off);
        s2 += __shfl_down(s2, off);
    }
    __shared__ float rs[4], rs2[4];
    int wave = tid >> 6;
    if ((tid & 63) == 0) { rs[wave] = s; rs2[wave] = s2; }
    __syncthreads();
    float sum = rs[grp * 2] + rs[grp * 2 + 1];
    float sumsq = rs2[grp * 2] + rs2[grp * 2 + 1];
    float mu = sum * (1.f / 128.f);
    float var = sumsq * (1.f / 128.f) - mu * mu;
    float r = rsqrtf(var + 1e-5f);
    if (valid) {
        float y = (t - mu) * r * ln_g[f] + ln_b[f];
        y = fmaxf(y, 0.f);
        y += U[(size_t)i * 256 + 128 + f] + bres[f];
        hb[(size_t)i * 128 + f] = f2bf(y);
    }
}

// ---------------- layer4 ----------------
__global__ __launch_bounds__(256) void pq_kernel(const unsigned short* __restrict__ hb, const float* __restrict__ Wl4,
                                                 const float* __restrict__ Wr4, const float* __restrict__ b4,
                                                 float* __restrict__ p, float* __restrict__ q) {
    int tid = threadIdx.x;
    int lane = tid & 63;
    int w = tid >> 6;
    int i = blockIdx.x * 4 + w;
    if (i >= N_NODES) return;
    const unsigned short* hr = hb + (size_t)i * 128;
    float a = bf2f(hr[lane]), b = bf2f(hr[64 + lane]);
    float pp = a * Wl4[lane] + b * Wl4[64 + lane];
    float qq = a * Wr4[lane] + b * Wr4[64 + lane];
    #pragma unroll
    for (int off = 32; off; off >>= 1) {
        pp += __shfl_down(pp, off);
        qq += __shfl_down(qq, off);
    }
    if (lane == 0) { p[i] = pp; q[i] = qq + b4[0]; }
}

__global__ __launch_bounds__(256) void final_kernel(const float* __restrict__ p, const float* __restrict__ q,
                                                    const int* __restrict__ row_ptr, const int* __restrict__ col,
                                                    const float* __restrict__ deg_inv, float* __restrict__ out) {
    int i = blockIdx.x * 256 + threadIdx.x;
    if (i >= N_NODES) return;
    int s = row_ptr[i], e = row_ptr[i + 1];
    float acc = 0.f;
    for (int t = s; t < e; t++) acc += p[col[t]];
    out[i] = acc * deg_inv[i] + q[i];
}

// ---------------- launch ----------------

extern "C" void kernel_launch(void* const* d_in, const int* in_sizes, int n_in,
                              void* d_out, int out_size, void* d_ws, size_t ws_size,
                              hipStream_t stream) {
    const float* x    = (const float*)d_in[0];
    const int*   ei   = (const int*)d_in[1];
    const float* Wl1  = (const float*)d_in[2];
    const float* Wr1  = (const float*)d_in[3];
    const float* b1   = (const float*)d_in[4];
    const float* ln_g = (const float*)d_in[5];
    const float* ln_b = (const float*)d_in[6];
    const float* Wres = (const float*)d_in[7];
    const float* bres = (const float*)d_in[8];
    const float* Wl2  = (const float*)d_in[9];
    const float* Wr2  = (const float*)d_in[10];
    const float* b2   = (const float*)d_in[11];
    const float* Wl3  = (const float*)d_in[12];
    const float* Wr3  = (const float*)d_in[13];
    const float* b3   = (const float*)d_in[14];
    const float* Wl4  = (const float*)d_in[15];
    const float* Wr4  = (const float*)d_in[16];
    const float* b4   = (const float*)d_in[17];
    float* out = (float*)d_out;

    char* w = (char*)d_ws;
    size_t off = 0;
    auto alloc = [&](size_t bytes) -> void* {
        off = (off + 255) & ~(size_t)255;
        void* pp = w + off;
        off += bytes;
        return pp;
    };

    int*   deg        = (int*)alloc(N_NODES * 4);
    int*   row_ptr    = (int*)alloc((N_NODES + 1) * 4);
    int*   bsum       = (int*)alloc(512);
    int*   col        = (int*)alloc(N_EDGES * 4);
    float* deg_inv    = (float*)alloc(N_NODES * 4);
    int*   bucket_cnt = (int*)alloc(NBKT * 4);
    int*   bucket_off = (int*)alloc((NBKT + 1) * 4);
    int*   cursor     = (int*)alloc(NBKT * 4);
    unsigned short* Btw  = (unsigned short*)alloc(256 * 128 * 2);
    unsigned short* xcat = (unsigned short*)alloc((size_t)N_NODES * 128 * 2);
    unsigned short* hb   = (unsigned short*)alloc((size_t)N_NODES * 128 * 2);
    float* U       = (float*)alloc((size_t)N_NODES * 256 * 4);
    float* p       = (float*)alloc(N_NODES * 4);
    float* q       = (float*)alloc(N_NODES * 4);
    // pairs aliases U: CSR build completes before U is first written (layer-1 GEMM)
    int2* pairs = (int2*)U;
    // layers 2/3 GEMM outputs alias U (102.4 MB >= 25.6 + 51.2 MB)
    unsigned short* Gl = (unsigned short*)U;                                    // N x 128 bf16
    float*          Gr = (float*)(((size_t)((char*)U + (size_t)N_NODES * 128 * 2) + 255) & ~(size_t)255);
    (void)ws_size; (void)n_in; (void)in_sizes; (void)out_size;

    const int NB = (N_NODES + 255) / 256;
    const int SCB = (N_NODES + SCAN_ELEMS - 1) / SCAN_ELEMS;
    const int MB = (N_NODES + 127) / 128;   // 782

    // --- CSR build (bucket counting sort, no global per-edge atomics) ---
    hipMemsetAsync(bucket_cnt, 0, NBKT * 4, stream);
    bkt_count_kernel<<<SCAT_BLOCKS, 256, 0, stream>>>(ei, bucket_cnt);
    bkt_scan_kernel<<<1, 256, 0, stream>>>(bucket_cnt, bucket_off, cursor);
    bkt_scatter_kernel<<<SCAT_BLOCKS, 256, 0, stream>>>(ei, cursor, pairs);
    bkt_deg_kernel<<<NBKT, 256, 0, stream>>>(pairs, bucket_off, deg);
    scan_a_kernel<<<SCB, 256, 0, stream>>>(deg, bsum);
    scan_b_kernel<<<1, 64, 0, stream>>>(bsum, SCB);
    scan_c_kernel<<<SCB, 256, 0, stream>>>(deg, bsum, row_ptr);
    bkt_fill_kernel<<<NBKT, 256, 0, stream>>>(pairs, bucket_off, row_ptr, col);
    deginv_kernel<<<NB, 256, 0, stream>>>(deg, deg_inv);

    // --- layer 1: A = [x | mean-agg(x)] bf16, B = [[Wr1|Wres],[Wl1|0]] ---
    xbf_kernel<<<(N_NODES * IN_F / 4 + 255) / 256, 256, 0, stream>>>(x, xcat);
    agg64_kernel<<<(N_NODES + 15) / 16, 256, 0, stream>>>(xcat, row_ptr, col, deg_inv, xcat);
    wprep1_kernel<<<128, 256, 0, stream>>>(Wr1, Wl1, Wres, Btw);
    mgemm_kernel<<<dim3(MB, 2), 256, 0, stream>>>(xcat, Btw, N_NODES, U, 256, 0, nullptr);
    ln_kernel<<<(N_NODES + 1) / 2, 256, 0, stream>>>(U, b1, ln_g, ln_b, bres, hb);

    // --- layer 2 ---
    wprep23_kernel<<<128, 256, 0, stream>>>(Wl2, Wr2, Btw);
    mgemm_kernel<<<dim3(MB, 2), 256, 0, stream>>>(hb, Btw, N_NODES, Gr, 128, 128, Gl);
    agg128_relu_kernel<<<(N_NODES + 7) / 8, 256, 0, stream>>>(Gl, Gr, row_ptr, col, deg_inv, b2, hb);

    // --- layer 3 ---
    wprep23_kernel<<<128, 256, 0, stream>>>(Wl3, Wr3, Btw);
    mgemm_kernel<<<dim3(MB, 2), 256, 0, stream>>>(hb, Btw, N_NODES, Gr, 128, 128, Gl);
    agg128_relu_kernel<<<(N_NODES + 7) / 8, 256, 0, stream>>>(Gl, Gr, row_ptr, col, deg_inv, b3, hb);

    // --- layer 4 ---
    pq_kernel<<<(N_NODES + 3) / 4, 256, 0, stream>>>(hb, Wl4, Wr4, b4, p, q);
    final_kernel<<<NB, 256, 0, stream>>>(p, q, row_ptr, col, deg_inv, out);
}